// Round 6
// baseline (500.236 us; speedup 1.0000x reference)
//
#include <hip/hip_runtime.h>

#define OBS_T 20
#define HID 128
#define NGATE 512
#define MB 16          // batch rows per block
#define HSTR 136       // hbuf row stride in bf16 (272B = 17*16B)

typedef __bf16 bf16x8 __attribute__((ext_vector_type(8)));
typedef __bf16 bf16x4 __attribute__((ext_vector_type(4)));
typedef float f32x4 __attribute__((ext_vector_type(4)));

__device__ __forceinline__ float fast_rcp(float x) { return __builtin_amdgcn_rcpf(x); }
#if __has_builtin(__builtin_amdgcn_exp2f)
__device__ __forceinline__ float exp2_hw(float x) { return __builtin_amdgcn_exp2f(x); }
#else
__device__ __forceinline__ float exp2_hw(float x) { return __expf(x * 0.69314718056f); }
#endif
#define LOG2E 1.442695041f

// ---- prep 1: fold embedding into rank-2 + bias, gate-major permutation ----
// gate row r = q*128 + j (torch order i,f,g,o). np = (j>>4)*64 + q*16 + (j&15)
__global__ void prep_vec(const float* __restrict__ W_emb, const float* __restrict__ b_emb,
                         const float* __restrict__ W_ih, const float* __restrict__ b_ih,
                         const float* __restrict__ b_hh,
                         float* __restrict__ biasp, float* __restrict__ wx0p,
                         float* __restrict__ wx1p) {
  int r = blockIdx.x * blockDim.x + threadIdx.x;
  if (r >= NGATE) return;
  float s0 = 0.f, s1 = 0.f, sb = 0.f;
  for (int d = 0; d < 64; ++d) {
    float w = W_ih[r * 64 + d];
    s0 += w * W_emb[d * 2 + 0];
    s1 += w * W_emb[d * 2 + 1];
    sb += w * b_emb[d];
  }
  int q = r >> 7, j = r & 127;
  int np = (j >> 4) * 64 + q * 16 + (j & 15);
  biasp[np] = b_ih[r] + b_hh[r] + sb;
  wx0p[np] = s0;
  wx1p[np] = s1;
}

// ---- prep 2: W_hh -> bf16 B-fragments, gate-major frag order ----
// frag f = g16*16 + q*4 + ks  (g16 = unit-group of 16) ; elem = (f*64 + lane)*8 + jj
// col n -> unit j = g16*16 + (lane&15), gate q => r = q*128 + g16*16 + cn
// k = ks*32 + (lane>>4)*8 + jj
__global__ void prep_wp(const float* __restrict__ W_hh, __bf16* __restrict__ Wp) {
  int tid = blockIdx.x * blockDim.x + threadIdx.x;  // 0..65535
  int jj = tid & 7;
  int lane = (tid >> 3) & 63;
  int frag = tid >> 9;  // 0..127
  int ks = frag & 3;
  int q = (frag >> 2) & 3;
  int g16 = frag >> 4;
  int cn = lane & 15, quad = lane >> 4;
  int r = q * 128 + g16 * 16 + cn;
  int k = ks * 32 + quad * 8 + jj;
  Wp[tid] = (__bf16)W_hh[r * 128 + k];
}

// lane-local LSTM cell, 5 exp2 + 2 rcp:
//   c' = rcp((1+e_i)(1+e_g)(1+e_f)) * [ c*(1+e_i)(1+e_g) + (1-e_g)(1+e_f) ]
//   h  = (1-e_c) * rcp((1+e_o)(1+e_c))
__device__ __forceinline__ float cell_update(float gi, float gf, float gg, float go,
                                             float& c) {
  float e_i = exp2_hw(gi * -LOG2E);
  float e_f = exp2_hw(gf * -LOG2E);
  float e_g = exp2_hw(gg * (-2.f * LOG2E));
  float e_o = exp2_hw(go * -LOG2E);
  float a_i = 1.f + e_i, a_f = 1.f + e_f, a_g = 1.f + e_g;
  float m1 = a_i * a_g;
  float r = fast_rcp(m1 * a_f);
  float t = fmaf(c, m1, (2.f - a_g) * a_f);
  c = t * r;
  float e_c = exp2_hw(c * (-2.f * LOG2E));
  float a_c = 1.f + e_c;
  return (2.f - a_c) * fast_rcp((1.f + e_o) * a_c);
}

// ---- main fused LSTM: 256 threads = 4 waves; wave wv owns unit-groups {2wv, 2wv+1}
// (32 units x 4 gates, Bf = 32 frags = 128 AGPRs). Each block puts 1 wave/SIMD;
// two blocks co-reside per CU with INDEPENDENT barriers -> stall overlap.
__global__ __launch_bounds__(256, 2) void lstm_fused(
    const float* __restrict__ obs, const float* __restrict__ h0,
    const float* __restrict__ c0, const __bf16* __restrict__ Wp,
    const float* __restrict__ biasp, const float* __restrict__ wx0p,
    const float* __restrict__ wx1p, float* __restrict__ out, int batch) {
  __shared__ __align__(16) __bf16 hbuf[2][MB][HSTR];
  __shared__ __align__(16) float obs_s[OBS_T][MB][2];

  const int tid = threadIdx.x;
  const int lane = tid & 63;
  const int wv = tid >> 6;  // 0..3
  const int cn = lane & 15;
  const int quad = lane >> 4;
  const int bbase = blockIdx.x * MB;
  const int ju0 = (wv * 2) * 16 + cn;   // unit-group 0 column
  const int ju1 = ju0 + 16;             // unit-group 1 column

  // stage obs tile: [20][16][2] fp32 = 160 float4
  if (tid < OBS_T * MB * 2 / 4) {
    const int t = tid >> 3, f4 = tid & 7;
    ((float4*)obs_s)[tid] = ((const float4*)obs)[(t * batch + bbase) / 2 + f4];
  }
  // stage h0 tile fp32 -> bf16 LDS: 16 rows x 32 float4 = 512
#pragma unroll
  for (int it = 0; it < 2; ++it) {
    int idx = tid + it * 256;
    int row = idx >> 5, c4 = idx & 31;
    float4 v = ((const float4*)h0)[(bbase + row) * 32 + c4];
    bf16x4 b;
    b.x = (__bf16)v.x; b.y = (__bf16)v.y; b.z = (__bf16)v.z; b.w = (__bf16)v.w;
    *(bf16x4*)&hbuf[0][row][c4 * 4] = b;
  }

  // persistent B fragments: 2 unit-groups x 4 gates x 4 ksteps = 128 regs
  bf16x8 Bf[2][4][4];  // [u][ks][q]
  {
    const bf16x8* wp8 = (const bf16x8*)Wp;
#pragma unroll
    for (int u = 0; u < 2; ++u)
#pragma unroll
      for (int q = 0; q < 4; ++q)
#pragma unroll
        for (int ks = 0; ks < 4; ++ks)
          Bf[u][ks][q] = wp8[((wv * 2 + u) * 16 + q * 4 + ks) * 64 + lane];
  }

  float bias_v[2][4], wx0_v[2][4], wx1_v[2][4];
#pragma unroll
  for (int u = 0; u < 2; ++u)
#pragma unroll
    for (int q = 0; q < 4; ++q) {
      int n = (wv * 2 + u) * 64 + q * 16 + cn;
      bias_v[u][q] = biasp[n];
      wx0_v[u][q] = wx0p[n];
      wx1_v[u][q] = wx1p[n];
    }

  // c state: [u][r], rows m = quad*4+r, col ju_u — fp32 in regs
  float cc[2][4];
#pragma unroll
  for (int r = 0; r < 4; ++r) {
    cc[0][r] = c0[(bbase + quad * 4 + r) * HID + ju0];
    cc[1][r] = c0[(bbase + quad * 4 + r) * HID + ju1];
  }

  __syncthreads();

  int cur = 0;
#pragma unroll 1
  for (int t = 0; t < OBS_T - 1; ++t) {
    f32x4 acc[2][4];  // [u][q]
#pragma unroll
    for (int r = 0; r < 4; ++r) {
      float2 ob = *(const float2*)&obs_s[t][quad * 4 + r][0];
#pragma unroll
      for (int u = 0; u < 2; ++u)
#pragma unroll
        for (int q = 0; q < 4; ++q)
          acc[u][q][r] = fmaf(ob.y, wx1_v[u][q], fmaf(ob.x, wx0_v[u][q], bias_v[u][q]));
    }

    // gates += h @ W_hh^T : 4 A-loads, 32 MFMAs (A shared by both unit-groups)
#pragma unroll
    for (int ks = 0; ks < 4; ++ks) {
      bf16x8 Av = *(const bf16x8*)&hbuf[cur][cn][ks * 32 + quad * 8];
#pragma unroll
      for (int q = 0; q < 4; ++q) {
        acc[0][q] = __builtin_amdgcn_mfma_f32_16x16x32_bf16(Av, Bf[0][ks][q], acc[0][q], 0, 0, 0);
        acc[1][q] = __builtin_amdgcn_mfma_f32_16x16x32_bf16(Av, Bf[1][ks][q], acc[1][q], 0, 0, 0);
      }
    }

    const int nxt = cur ^ 1;
#pragma unroll
    for (int r = 0; r < 4; ++r) {
      float h0v = cell_update(acc[0][0][r], acc[0][1][r], acc[0][2][r], acc[0][3][r], cc[0][r]);
      float h1v = cell_update(acc[1][0][r], acc[1][1][r], acc[1][2][r], acc[1][3][r], cc[1][r]);
      hbuf[nxt][quad * 4 + r][ju0] = (__bf16)h0v;
      hbuf[nxt][quad * 4 + r][ju1] = (__bf16)h1v;
    }
    __syncthreads();
    cur = nxt;
  }

  // peeled final step: h straight to global
  {
    const int t = OBS_T - 1;
    f32x4 acc[2][4];
#pragma unroll
    for (int r = 0; r < 4; ++r) {
      float2 ob = *(const float2*)&obs_s[t][quad * 4 + r][0];
#pragma unroll
      for (int u = 0; u < 2; ++u)
#pragma unroll
        for (int q = 0; q < 4; ++q)
          acc[u][q][r] = fmaf(ob.y, wx1_v[u][q], fmaf(ob.x, wx0_v[u][q], bias_v[u][q]));
    }
#pragma unroll
    for (int ks = 0; ks < 4; ++ks) {
      bf16x8 Av = *(const bf16x8*)&hbuf[cur][cn][ks * 32 + quad * 8];
#pragma unroll
      for (int q = 0; q < 4; ++q) {
        acc[0][q] = __builtin_amdgcn_mfma_f32_16x16x32_bf16(Av, Bf[0][ks][q], acc[0][q], 0, 0, 0);
        acc[1][q] = __builtin_amdgcn_mfma_f32_16x16x32_bf16(Av, Bf[1][ks][q], acc[1][q], 0, 0, 0);
      }
    }
#pragma unroll
    for (int r = 0; r < 4; ++r) {
      float h0v = cell_update(acc[0][0][r], acc[0][1][r], acc[0][2][r], acc[0][3][r], cc[0][r]);
      float h1v = cell_update(acc[1][0][r], acc[1][1][r], acc[1][2][r], acc[1][3][r], cc[1][r]);
      out[(bbase + quad * 4 + r) * HID + ju0] = h0v;
      out[(bbase + quad * 4 + r) * HID + ju1] = h1v;
    }
  }
}

extern "C" void kernel_launch(void* const* d_in, const int* in_sizes, int n_in,
                              void* d_out, int out_size, void* d_ws, size_t ws_size,
                              hipStream_t stream) {
  const float* obs = (const float*)d_in[0];
  const float* h0 = (const float*)d_in[1];
  const float* c0 = (const float*)d_in[2];
  const float* W_emb = (const float*)d_in[3];
  const float* b_emb = (const float*)d_in[4];
  const float* W_ih = (const float*)d_in[5];
  const float* W_hh = (const float*)d_in[6];
  const float* b_ih = (const float*)d_in[7];
  const float* b_hh = (const float*)d_in[8];
  float* out = (float*)d_out;
  const int batch = in_sizes[1] / HID;

  __bf16* Wp = (__bf16*)d_ws;                     // 65536 bf16 = 128 KB
  float* biasp = (float*)((char*)d_ws + 131072);  // 3 x 512 f32
  float* wx0p = biasp + NGATE;
  float* wx1p = wx0p + NGATE;

  prep_vec<<<2, 256, 0, stream>>>(W_emb, b_emb, W_ih, b_ih, b_hh, biasp, wx0p, wx1p);
  prep_wp<<<256, 256, 0, stream>>>(W_hh, Wp);
  lstm_fused<<<batch / MB, 256, 0, stream>>>(obs, h0, c0, Wp, biasp, wx0p, wx1p, out, batch);
}

// Round 8
// 374.800 us; speedup vs baseline: 1.3347x; 1.3347x over previous
//
#include <hip/hip_runtime.h>

#define OBS_T 20
#define HID 128
#define NGATE 512
#define MB 16          // batch rows per block
#define HSTR 136       // hbuf row stride in bf16 (272B = 17*16B)

typedef __bf16 bf16x8 __attribute__((ext_vector_type(8)));
typedef __bf16 bf16x4 __attribute__((ext_vector_type(4)));
typedef float f32x4 __attribute__((ext_vector_type(4)));

__device__ __forceinline__ float fast_rcp(float x) { return __builtin_amdgcn_rcpf(x); }
#if __has_builtin(__builtin_amdgcn_exp2f)
__device__ __forceinline__ float exp2_hw(float x) { return __builtin_amdgcn_exp2f(x); }
#else
__device__ __forceinline__ float exp2_hw(float x) { return __expf(x * 0.69314718056f); }
#endif
#define LOG2E 1.442695041f

// ---- prep 1: fold embedding into rank-2 + bias, gate-major permutation ----
// gate row r = q*128 + j (torch i,f,g,o). np = (j>>4)*64 + q*16 + (j&15)
__global__ void prep_vec(const float* __restrict__ W_emb, const float* __restrict__ b_emb,
                         const float* __restrict__ W_ih, const float* __restrict__ b_ih,
                         const float* __restrict__ b_hh,
                         float* __restrict__ biasp, float* __restrict__ wx0p,
                         float* __restrict__ wx1p) {
  int r = blockIdx.x * blockDim.x + threadIdx.x;
  if (r >= NGATE) return;
  float s0 = 0.f, s1 = 0.f, sb = 0.f;
  for (int d = 0; d < 64; ++d) {
    float w = W_ih[r * 64 + d];
    s0 += w * W_emb[d * 2 + 0];
    s1 += w * W_emb[d * 2 + 1];
    sb += w * b_emb[d];
  }
  int q = r >> 7, j = r & 127;
  int np = (j >> 4) * 64 + q * 16 + (j & 15);
  biasp[np] = b_ih[r] + b_hh[r] + sb;
  wx0p[np] = s0;
  wx1p[np] = s1;
}

// ---- prep 2: W_hh -> bf16 B-fragments (identical to passing r6) ----
// frag f = g16*16 + q*4 + ks ; elem = (f*64 + lane)*8 + jj
// col n -> unit j = g16*16 + (lane&15), gate q => r = q*128 + g16*16 + cn
// k = ks*32 + (lane>>4)*8 + jj
__global__ void prep_wp(const float* __restrict__ W_hh, __bf16* __restrict__ Wp) {
  int tid = blockIdx.x * blockDim.x + threadIdx.x;  // 0..65535
  int jj = tid & 7;
  int lane = (tid >> 3) & 63;
  int frag = tid >> 9;  // 0..127
  int ks = frag & 3;
  int q = (frag >> 2) & 3;
  int g16 = frag >> 4;
  int cn = lane & 15, quad = lane >> 4;
  int r = q * 128 + g16 * 16 + cn;
  int k = ks * 32 + quad * 8 + jj;
  Wp[tid] = (__bf16)W_hh[r * 128 + k];
}

// lane-local LSTM cell, 5 exp2 + 2 rcp (proven r5/r6, absmax 1.95e-3):
//   c' = rcp((1+e_i)(1+e_g)(1+e_f)) * [ c*(1+e_i)(1+e_g) + (1-e_g)(1+e_f) ]
//   h  = (1-e_c) * rcp((1+e_o)(1+e_c))
__device__ __forceinline__ float cell_update(float gi, float gf, float gg, float go,
                                             float& c) {
  float e_i = exp2_hw(gi * -LOG2E);
  float e_f = exp2_hw(gf * -LOG2E);
  float e_g = exp2_hw(gg * (-2.f * LOG2E));
  float e_o = exp2_hw(go * -LOG2E);
  float a_i = 1.f + e_i, a_f = 1.f + e_f, a_g = 1.f + e_g;
  float m1 = a_i * a_g;
  float r = fast_rcp(m1 * a_f);
  float t = fmaf(c, m1, (2.f - a_g) * a_f);
  c = t * r;
  float e_c = exp2_hw(c * (-2.f * LOG2E));
  float a_c = 1.f + e_c;
  return (2.f - a_c) * fast_rcp((1.f + e_o) * a_c);
}

// ---- main fused LSTM: 256 threads = 4 waves; wave wv owns unit-groups
// {2wv, 2wv+1} (r6's PROVEN mapping), processed sequentially per step sharing
// one acc set. Bias/wx live in LDS tables (broadcast reads) instead of regs.
// ~195 unified regs < 256 cap -> no spill; 2 independent blocks/CU overlap.
__global__ __launch_bounds__(256, 2) void lstm_fused(
    const float* __restrict__ obs, const float* __restrict__ h0,
    const float* __restrict__ c0, const __bf16* __restrict__ Wp,
    const float* __restrict__ biasp, const float* __restrict__ wx0p,
    const float* __restrict__ wx1p, float* __restrict__ out, int batch) {
  __shared__ __align__(16) __bf16 hbuf[2][MB][HSTR];
  __shared__ __align__(16) float obs_s[OBS_T][MB][2];
  __shared__ __align__(16) float bias_s[NGATE];
  __shared__ __align__(16) float wx0_s[NGATE];
  __shared__ __align__(16) float wx1_s[NGATE];

  const int tid = threadIdx.x;
  const int lane = tid & 63;
  const int wv = tid >> 6;  // 0..3
  const int cn = lane & 15;
  const int quad = lane >> 4;
  const int bbase = blockIdx.x * MB;
  const int ju0 = (wv * 2) * 16 + cn;  // unit-group 0 column
  const int ju1 = ju0 + 16;            // unit-group 1 column

  // stage obs tile: [20][16][2] fp32 = 160 float4
  if (tid < OBS_T * MB * 2 / 4) {
    const int t = tid >> 3, f4 = tid & 7;
    ((float4*)obs_s)[tid] = ((const float4*)obs)[(t * batch + bbase) / 2 + f4];
  }
  // stage bias/wx tables: 3 x 512 floats
#pragma unroll
  for (int it = 0; it < 2; ++it) {
    int i = tid + it * 256;
    bias_s[i] = biasp[i];
    wx0_s[i] = wx0p[i];
    wx1_s[i] = wx1p[i];
  }
  // stage h0 tile fp32 -> bf16 LDS: 16 rows x 32 float4 = 512
#pragma unroll
  for (int it = 0; it < 2; ++it) {
    int idx = tid + it * 256;
    int row = idx >> 5, c4 = idx & 31;
    float4 v = ((const float4*)h0)[(bbase + row) * 32 + c4];
    bf16x4 b;
    b.x = (__bf16)v.x; b.y = (__bf16)v.y; b.z = (__bf16)v.z; b.w = (__bf16)v.w;
    *(bf16x4*)&hbuf[0][row][c4 * 4] = b;
  }

  // persistent B fragments: 2 unit-groups x 4 gates x 4 ksteps = 128 regs (r6 mapping)
  bf16x8 Bf[2][4][4];  // [u][ks][q]
  {
    const bf16x8* wp8 = (const bf16x8*)Wp;
#pragma unroll
    for (int u = 0; u < 2; ++u)
#pragma unroll
      for (int q = 0; q < 4; ++q)
#pragma unroll
        for (int ks = 0; ks < 4; ++ks)
          Bf[u][ks][q] = wp8[((wv * 2 + u) * 16 + q * 4 + ks) * 64 + lane];
  }

  // c state: [u][r], rows m = quad*4+r, col ju_u — fp32 in regs (r6 mapping)
  float cc[2][4];
#pragma unroll
  for (int r = 0; r < 4; ++r) {
    cc[0][r] = c0[(bbase + quad * 4 + r) * HID + ju0];
    cc[1][r] = c0[(bbase + quad * 4 + r) * HID + ju1];
  }

  __syncthreads();

  int cur = 0;
#pragma unroll 1
  for (int t = 0; t < OBS_T - 1; ++t) {
    float2 ob[4];
#pragma unroll
    for (int r = 0; r < 4; ++r) ob[r] = *(const float2*)&obs_s[t][quad * 4 + r][0];

    const int nxt = cur ^ 1;
#pragma unroll
    for (int u = 0; u < 2; ++u) {
      const int ju = ju0 + u * 16;
      f32x4 acc[4];
#pragma unroll
      for (int q = 0; q < 4; ++q) {
        int n = (wv * 2 + u) * 64 + q * 16 + cn;
        float bq = bias_s[n], w0q = wx0_s[n], w1q = wx1_s[n];
#pragma unroll
        for (int r = 0; r < 4; ++r)
          acc[q][r] = fmaf(ob[r].y, w1q, fmaf(ob[r].x, w0q, bq));
      }
#pragma unroll
      for (int ks = 0; ks < 4; ++ks) {
        bf16x8 Av = *(const bf16x8*)&hbuf[cur][cn][ks * 32 + quad * 8];
#pragma unroll
        for (int q = 0; q < 4; ++q)
          acc[q] = __builtin_amdgcn_mfma_f32_16x16x32_bf16(Av, Bf[u][ks][q], acc[q], 0, 0, 0);
      }
#pragma unroll
      for (int r = 0; r < 4; ++r) {
        float h = cell_update(acc[0][r], acc[1][r], acc[2][r], acc[3][r], cc[u][r]);
        hbuf[nxt][quad * 4 + r][ju] = (__bf16)h;
      }
    }
    __syncthreads();
    cur = nxt;
  }

  // peeled final step: h straight to global
  {
    const int t = OBS_T - 1;
    float2 ob[4];
#pragma unroll
    for (int r = 0; r < 4; ++r) ob[r] = *(const float2*)&obs_s[t][quad * 4 + r][0];
#pragma unroll
    for (int u = 0; u < 2; ++u) {
      const int ju = ju0 + u * 16;
      f32x4 acc[4];
#pragma unroll
      for (int q = 0; q < 4; ++q) {
        int n = (wv * 2 + u) * 64 + q * 16 + cn;
        float bq = bias_s[n], w0q = wx0_s[n], w1q = wx1_s[n];
#pragma unroll
        for (int r = 0; r < 4; ++r)
          acc[q][r] = fmaf(ob[r].y, w1q, fmaf(ob[r].x, w0q, bq));
      }
#pragma unroll
      for (int ks = 0; ks < 4; ++ks) {
        bf16x8 Av = *(const bf16x8*)&hbuf[cur][cn][ks * 32 + quad * 8];
#pragma unroll
        for (int q = 0; q < 4; ++q)
          acc[q] = __builtin_amdgcn_mfma_f32_16x16x32_bf16(Av, Bf[u][ks][q], acc[q], 0, 0, 0);
      }
#pragma unroll
      for (int r = 0; r < 4; ++r) {
        float h = cell_update(acc[0][r], acc[1][r], acc[2][r], acc[3][r], cc[u][r]);
        out[(bbase + quad * 4 + r) * HID + ju] = h;
      }
    }
  }
}

extern "C" void kernel_launch(void* const* d_in, const int* in_sizes, int n_in,
                              void* d_out, int out_size, void* d_ws, size_t ws_size,
                              hipStream_t stream) {
  const float* obs = (const float*)d_in[0];
  const float* h0 = (const float*)d_in[1];
  const float* c0 = (const float*)d_in[2];
  const float* W_emb = (const float*)d_in[3];
  const float* b_emb = (const float*)d_in[4];
  const float* W_ih = (const float*)d_in[5];
  const float* W_hh = (const float*)d_in[6];
  const float* b_ih = (const float*)d_in[7];
  const float* b_hh = (const float*)d_in[8];
  float* out = (float*)d_out;
  const int batch = in_sizes[1] / HID;

  __bf16* Wp = (__bf16*)d_ws;                     // 65536 bf16 = 128 KB
  float* biasp = (float*)((char*)d_ws + 131072);  // 3 x 512 f32 (same as r6)
  float* wx0p = biasp + NGATE;
  float* wx1p = wx0p + NGATE;

  prep_vec<<<2, 256, 0, stream>>>(W_emb, b_emb, W_ih, b_ih, b_hh, biasp, wx0p, wx1p);
  prep_wp<<<256, 256, 0, stream>>>(W_hh, Wp);
  lstm_fused<<<batch / MB, 256, 0, stream>>>(obs, h0, c0, Wp, biasp, wx0p, wx1p, out, batch);
}

// Round 10
// 358.778 us; speedup vs baseline: 1.3943x; 1.0447x over previous
//
#include <hip/hip_runtime.h>

#define OBS_T 20
#define HID 128
#define NGATE 512
#define MB 16          // batch rows per block
#define HSTR 136       // hbuf row stride in bf16 (272B = 17*16B)

typedef __bf16 bf16x8 __attribute__((ext_vector_type(8)));
typedef __bf16 bf16x4 __attribute__((ext_vector_type(4)));
typedef float f32x4 __attribute__((ext_vector_type(4)));

__device__ __forceinline__ float fast_rcp(float x) { return __builtin_amdgcn_rcpf(x); }
#if __has_builtin(__builtin_amdgcn_exp2f)
__device__ __forceinline__ float exp2_hw(float x) { return __builtin_amdgcn_exp2f(x); }
#else
__device__ __forceinline__ float exp2_hw(float x) { return __expf(x * 0.69314718056f); }
#endif
#define LOG2E 1.442695041f

// ---- prep 1: fold embedding into rank-2 + bias, gate-major permutation ----
// gate row r = q*128 + j (torch i,f,g,o). np = (j>>4)*64 + q*16 + (j&15)
// SCALAR tables (r8-proven; float4-packed variant failed twice — r7, r9)
__global__ void prep_vec(const float* __restrict__ W_emb, const float* __restrict__ b_emb,
                         const float* __restrict__ W_ih, const float* __restrict__ b_ih,
                         const float* __restrict__ b_hh,
                         float* __restrict__ biasp, float* __restrict__ wx0p,
                         float* __restrict__ wx1p) {
  int r = blockIdx.x * blockDim.x + threadIdx.x;
  if (r >= NGATE) return;
  float s0 = 0.f, s1 = 0.f, sb = 0.f;
  for (int d = 0; d < 64; ++d) {
    float w = W_ih[r * 64 + d];
    s0 += w * W_emb[d * 2 + 0];
    s1 += w * W_emb[d * 2 + 1];
    sb += w * b_emb[d];
  }
  int q = r >> 7, j = r & 127;
  int np = (j >> 4) * 64 + q * 16 + (j & 15);
  biasp[np] = b_ih[r] + b_hh[r] + sb;
  wx0p[np] = s0;
  wx1p[np] = s1;
}

// ---- prep 2: W_hh -> bf16 B-fragments (identical to passing r6/r8) ----
// frag f = g16*16 + q*4 + ks ; elem = (f*64 + lane)*8 + jj
// col n -> unit j = g16*16 + (lane&15), gate q => r = q*128 + g16*16 + cn
// k = ks*32 + (lane>>4)*8 + jj
__global__ void prep_wp(const float* __restrict__ W_hh, __bf16* __restrict__ Wp) {
  int tid = blockIdx.x * blockDim.x + threadIdx.x;  // 0..65535
  int jj = tid & 7;
  int lane = (tid >> 3) & 63;
  int frag = tid >> 9;  // 0..127
  int ks = frag & 3;
  int q = (frag >> 2) & 3;
  int g16 = frag >> 4;
  int cn = lane & 15, quad = lane >> 4;
  int r = q * 128 + g16 * 16 + cn;
  int k = ks * 32 + quad * 8 + jj;
  Wp[tid] = (__bf16)W_hh[r * 128 + k];
}

// lane-local LSTM cell, 5 exp2 + 2 rcp (proven r5/r6/r8, absmax 1.95e-3):
//   c' = rcp((1+e_i)(1+e_g)(1+e_f)) * [ c*(1+e_i)(1+e_g) + (1-e_g)(1+e_f) ]
//   h  = (1-e_c) * rcp((1+e_o)(1+e_c))
__device__ __forceinline__ float cell_update(float gi, float gf, float gg, float go,
                                             float& c) {
  float e_i = exp2_hw(gi * -LOG2E);
  float e_f = exp2_hw(gf * -LOG2E);
  float e_g = exp2_hw(gg * (-2.f * LOG2E));
  float e_o = exp2_hw(go * -LOG2E);
  float a_i = 1.f + e_i, a_f = 1.f + e_f, a_g = 1.f + e_g;
  float m1 = a_i * a_g;
  float r = fast_rcp(m1 * a_f);
  float t = fmaf(c, m1, (2.f - a_g) * a_f);
  c = t * r;
  float e_c = exp2_hw(c * (-2.f * LOG2E));
  float a_c = 1.f + e_c;
  return (2.f - a_c) * fast_rcp((1.f + e_o) * a_c);
}

// ---- main fused LSTM: 256 threads = 4 waves; wave wv owns unit-groups
// {2wv, 2wv+1} (r6/r8 PROVEN mapping). Merged-u step body (r6-proven):
// one shared A-load per ks, 32 MFMAs, then all 8 cell_updates together.
// Bias/wx from SCALAR LDS tables (r8-proven). ~252 unified regs <= 256 cap.
__global__ __launch_bounds__(256, 2) void lstm_fused(
    const float* __restrict__ obs, const float* __restrict__ h0,
    const float* __restrict__ c0, const __bf16* __restrict__ Wp,
    const float* __restrict__ biasp, const float* __restrict__ wx0p,
    const float* __restrict__ wx1p, float* __restrict__ out, int batch) {
  __shared__ __align__(16) __bf16 hbuf[2][MB][HSTR];
  __shared__ __align__(16) float obs_s[OBS_T][MB][2];
  __shared__ __align__(16) float bias_s[NGATE];
  __shared__ __align__(16) float wx0_s[NGATE];
  __shared__ __align__(16) float wx1_s[NGATE];

  const int tid = threadIdx.x;
  const int lane = tid & 63;
  const int wv = tid >> 6;  // 0..3
  const int cn = lane & 15;
  const int quad = lane >> 4;
  const int bbase = blockIdx.x * MB;
  const int ju0 = (wv * 2) * 16 + cn;  // unit-group 0 column
  const int ju1 = ju0 + 16;            // unit-group 1 column

  // stage obs tile: [20][16][2] fp32 = 160 float4
  if (tid < OBS_T * MB * 2 / 4) {
    const int t = tid >> 3, f4 = tid & 7;
    ((float4*)obs_s)[tid] = ((const float4*)obs)[(t * batch + bbase) / 2 + f4];
  }
  // stage bias/wx tables: 3 x 512 floats (r8-proven scalar form)
#pragma unroll
  for (int it = 0; it < 2; ++it) {
    int i = tid + it * 256;
    bias_s[i] = biasp[i];
    wx0_s[i] = wx0p[i];
    wx1_s[i] = wx1p[i];
  }
  // stage h0 tile fp32 -> bf16 LDS: 16 rows x 32 float4 = 512
#pragma unroll
  for (int it = 0; it < 2; ++it) {
    int idx = tid + it * 256;
    int row = idx >> 5, c4 = idx & 31;
    float4 v = ((const float4*)h0)[(bbase + row) * 32 + c4];
    bf16x4 b;
    b.x = (__bf16)v.x; b.y = (__bf16)v.y; b.z = (__bf16)v.z; b.w = (__bf16)v.w;
    *(bf16x4*)&hbuf[0][row][c4 * 4] = b;
  }

  // persistent B fragments: 2 unit-groups x 4 gates x 4 ksteps = 128 regs
  bf16x8 Bf[2][4][4];  // [u][ks][q]
  {
    const bf16x8* wp8 = (const bf16x8*)Wp;
#pragma unroll
    for (int u = 0; u < 2; ++u)
#pragma unroll
      for (int q = 0; q < 4; ++q)
#pragma unroll
        for (int ks = 0; ks < 4; ++ks)
          Bf[u][ks][q] = wp8[((wv * 2 + u) * 16 + q * 4 + ks) * 64 + lane];
  }

  // c state: [u][r], rows m = quad*4+r, col ju_u — fp32 in regs
  float cc[2][4];
#pragma unroll
  for (int r = 0; r < 4; ++r) {
    cc[0][r] = c0[(bbase + quad * 4 + r) * HID + ju0];
    cc[1][r] = c0[(bbase + quad * 4 + r) * HID + ju1];
  }

  __syncthreads();

  int cur = 0;
#pragma unroll 1
  for (int t = 0; t < OBS_T - 1; ++t) {
    // acc init for BOTH groups: bias + rank-2 folded embedding (fp32, exact)
    f32x4 acc[2][4];  // [u][q]
#pragma unroll
    for (int u = 0; u < 2; ++u)
#pragma unroll
      for (int q = 0; q < 4; ++q) {
        int n = (wv * 2 + u) * 64 + q * 16 + cn;
        float bq = bias_s[n], w0q = wx0_s[n], w1q = wx1_s[n];
#pragma unroll
        for (int r = 0; r < 4; ++r) {
          float2 ob = *(const float2*)&obs_s[t][quad * 4 + r][0];
          acc[u][q][r] = fmaf(ob.y, w1q, fmaf(ob.x, w0q, bq));
        }
      }

    // gates += h @ W_hh^T : ONE A-load per ks shared by both groups, 32 MFMAs
#pragma unroll
    for (int ks = 0; ks < 4; ++ks) {
      bf16x8 Av = *(const bf16x8*)&hbuf[cur][cn][ks * 32 + quad * 8];
#pragma unroll
      for (int q = 0; q < 4; ++q) {
        acc[0][q] = __builtin_amdgcn_mfma_f32_16x16x32_bf16(Av, Bf[0][ks][q], acc[0][q], 0, 0, 0);
        acc[1][q] = __builtin_amdgcn_mfma_f32_16x16x32_bf16(Av, Bf[1][ks][q], acc[1][q], 0, 0, 0);
      }
    }

    // all 8 cell updates together (max transcendental ILP)
    const int nxt = cur ^ 1;
#pragma unroll
    for (int r = 0; r < 4; ++r) {
      float h0v = cell_update(acc[0][0][r], acc[0][1][r], acc[0][2][r], acc[0][3][r], cc[0][r]);
      float h1v = cell_update(acc[1][0][r], acc[1][1][r], acc[1][2][r], acc[1][3][r], cc[1][r]);
      hbuf[nxt][quad * 4 + r][ju0] = (__bf16)h0v;
      hbuf[nxt][quad * 4 + r][ju1] = (__bf16)h1v;
    }
    __syncthreads();
    cur = nxt;
  }

  // peeled final step: h straight to global
  {
    const int t = OBS_T - 1;
    f32x4 acc[2][4];
#pragma unroll
    for (int u = 0; u < 2; ++u)
#pragma unroll
      for (int q = 0; q < 4; ++q) {
        int n = (wv * 2 + u) * 64 + q * 16 + cn;
        float bq = bias_s[n], w0q = wx0_s[n], w1q = wx1_s[n];
#pragma unroll
        for (int r = 0; r < 4; ++r) {
          float2 ob = *(const float2*)&obs_s[t][quad * 4 + r][0];
          acc[u][q][r] = fmaf(ob.y, w1q, fmaf(ob.x, w0q, bq));
        }
      }
#pragma unroll
    for (int ks = 0; ks < 4; ++ks) {
      bf16x8 Av = *(const bf16x8*)&hbuf[cur][cn][ks * 32 + quad * 8];
#pragma unroll
      for (int q = 0; q < 4; ++q) {
        acc[0][q] = __builtin_amdgcn_mfma_f32_16x16x32_bf16(Av, Bf[0][ks][q], acc[0][q], 0, 0, 0);
        acc[1][q] = __builtin_amdgcn_mfma_f32_16x16x32_bf16(Av, Bf[1][ks][q], acc[1][q], 0, 0, 0);
      }
    }
#pragma unroll
    for (int r = 0; r < 4; ++r) {
      float h0v = cell_update(acc[0][0][r], acc[0][1][r], acc[0][2][r], acc[0][3][r], cc[0][r]);
      float h1v = cell_update(acc[1][0][r], acc[1][1][r], acc[1][2][r], acc[1][3][r], cc[1][r]);
      out[(bbase + quad * 4 + r) * HID + ju0] = h0v;
      out[(bbase + quad * 4 + r) * HID + ju1] = h1v;
    }
  }
}

extern "C" void kernel_launch(void* const* d_in, const int* in_sizes, int n_in,
                              void* d_out, int out_size, void* d_ws, size_t ws_size,
                              hipStream_t stream) {
  const float* obs = (const float*)d_in[0];
  const float* h0 = (const float*)d_in[1];
  const float* c0 = (const float*)d_in[2];
  const float* W_emb = (const float*)d_in[3];
  const float* b_emb = (const float*)d_in[4];
  const float* W_ih = (const float*)d_in[5];
  const float* W_hh = (const float*)d_in[6];
  const float* b_ih = (const float*)d_in[7];
  const float* b_hh = (const float*)d_in[8];
  float* out = (float*)d_out;
  const int batch = in_sizes[1] / HID;

  __bf16* Wp = (__bf16*)d_ws;                     // 65536 bf16 = 128 KB
  float* biasp = (float*)((char*)d_ws + 131072);  // 3 x 512 f32 (r8 layout)
  float* wx0p = biasp + NGATE;
  float* wx1p = wx0p + NGATE;

  prep_vec<<<2, 256, 0, stream>>>(W_emb, b_emb, W_ih, b_ih, b_hh, biasp, wx0p, wx1p);
  prep_wp<<<256, 256, 0, stream>>>(W_hh, Wp);
  lstm_fused<<<batch / MB, 256, 0, stream>>>(obs, h0, c0, Wp, biasp, wx0p, wx1p, out, batch);
}

// Round 11
// 342.297 us; speedup vs baseline: 1.4614x; 1.0481x over previous
//
#include <hip/hip_runtime.h>

#define OBS_T 20
#define HID 128
#define NGATE 512
#define MB 16          // batch rows per block
#define HSTR 136       // hbuf row stride in bf16 (272B = 17*16B)

typedef __bf16 bf16x8 __attribute__((ext_vector_type(8)));
typedef __bf16 bf16x4 __attribute__((ext_vector_type(4)));
typedef float f32x4 __attribute__((ext_vector_type(4)));

__device__ __forceinline__ float fast_rcp(float x) { return __builtin_amdgcn_rcpf(x); }
#if __has_builtin(__builtin_amdgcn_exp2f)
__device__ __forceinline__ float exp2_hw(float x) { return __builtin_amdgcn_exp2f(x); }
#else
__device__ __forceinline__ float exp2_hw(float x) { return __expf(x * 0.69314718056f); }
#endif
#define LOG2E 1.442695041f

// gate scale: preacts arrive PRE-SCALED by s_q so exp2 needs no mul.
// s_q = -LOG2E for i,f,o ; -2*LOG2E for g (since tanh uses e^{-2x})
__device__ __host__ __forceinline__ float gate_scale(int q) {
  return (q == 2) ? (-2.0f * LOG2E) : (-LOG2E);
}

// ---- prep 1: fold embedding into rank-2 + bias, gate-major permutation ----
// gate row r = q*128 + j (torch i,f,g,o). np = (j>>4)*64 + q*16 + (j&15)
// SCALAR tables (r8/r10-proven; float4-packed variant failed twice — banned).
// Values pre-scaled by gate_scale(q).
__global__ void prep_vec(const float* __restrict__ W_emb, const float* __restrict__ b_emb,
                         const float* __restrict__ W_ih, const float* __restrict__ b_ih,
                         const float* __restrict__ b_hh,
                         float* __restrict__ biasp, float* __restrict__ wx0p,
                         float* __restrict__ wx1p) {
  int r = blockIdx.x * blockDim.x + threadIdx.x;
  if (r >= NGATE) return;
  float s0 = 0.f, s1 = 0.f, sb = 0.f;
  for (int d = 0; d < 64; ++d) {
    float w = W_ih[r * 64 + d];
    s0 += w * W_emb[d * 2 + 0];
    s1 += w * W_emb[d * 2 + 1];
    sb += w * b_emb[d];
  }
  int q = r >> 7, j = r & 127;
  float sc = gate_scale(q);
  int np = (j >> 4) * 64 + q * 16 + (j & 15);
  biasp[np] = (b_ih[r] + b_hh[r] + sb) * sc;
  wx0p[np] = s0 * sc;
  wx1p[np] = s1 * sc;
}

// ---- prep 2: W_hh -> bf16 B-fragments (r6/r8/r10 mapping), PRE-SCALED ----
// frag f = g16*16 + q*4 + ks ; elem = (f*64 + lane)*8 + jj
// col n -> unit j = g16*16 + (lane&15), gate q => r = q*128 + g16*16 + cn
// k = ks*32 + (lane>>4)*8 + jj ; value = W_hh[r][k] * gate_scale(q)
__global__ void prep_wp(const float* __restrict__ W_hh, __bf16* __restrict__ Wp) {
  int tid = blockIdx.x * blockDim.x + threadIdx.x;  // 0..65535
  int jj = tid & 7;
  int lane = (tid >> 3) & 63;
  int frag = tid >> 9;  // 0..127
  int ks = frag & 3;
  int q = (frag >> 2) & 3;
  int g16 = frag >> 4;
  int cn = lane & 15, quad = lane >> 4;
  int r = q * 128 + g16 * 16 + cn;
  int k = ks * 32 + quad * 8 + jj;
  Wp[tid] = (__bf16)(W_hh[r * 128 + k] * gate_scale(q));
}

// lane-local LSTM cell on PRE-SCALED preacts (gi=-log2e*i, gg=-2log2e*g, ...):
//   c' = rcp((1+e_i)(1+e_g)(1+e_f)) * [ c*(1+e_i)(1+e_g) + (1-e_g)(1+e_f) ]
//   h  = (1-e_c) * rcp((1+e_o)(1+e_c))
// (same math as r5..r10, absmax 1.95e-3; only the pre-scale muls moved to prep)
__device__ __forceinline__ float cell_update(float gi, float gf, float gg, float go,
                                             float& c) {
  float e_i = exp2_hw(gi);
  float e_f = exp2_hw(gf);
  float e_g = exp2_hw(gg);
  float e_o = exp2_hw(go);
  float a_i = 1.f + e_i, a_f = 1.f + e_f, a_g = 1.f + e_g;
  float m1 = a_i * a_g;
  float r = fast_rcp(m1 * a_f);
  float t = fmaf(c, m1, (2.f - a_g) * a_f);
  c = t * r;
  float e_c = exp2_hw(c * (-2.f * LOG2E));
  float a_c = 1.f + e_c;
  return (2.f - a_c) * fast_rcp((1.f + e_o) * a_c);
}

// ---- main fused LSTM: 256 threads = 4 waves; wave wv owns unit-groups
// {2wv, 2wv+1} (r10 PROVEN). Merged-u step body: one shared A-load per ks,
// 32 MFMAs, then all 8 cell_updates together. Bias hoisted to regs (8);
// wx0/wx1 from scalar LDS tables. ~252 unified regs <= 256 cap.
__global__ __launch_bounds__(256, 2) void lstm_fused(
    const float* __restrict__ obs, const float* __restrict__ h0,
    const float* __restrict__ c0, const __bf16* __restrict__ Wp,
    const float* __restrict__ biasp, const float* __restrict__ wx0p,
    const float* __restrict__ wx1p, float* __restrict__ out, int batch) {
  __shared__ __align__(16) __bf16 hbuf[2][MB][HSTR];
  __shared__ __align__(16) float obs_s[OBS_T][MB][2];
  __shared__ __align__(16) float wx0_s[NGATE];
  __shared__ __align__(16) float wx1_s[NGATE];

  const int tid = threadIdx.x;
  const int lane = tid & 63;
  const int wv = tid >> 6;  // 0..3
  const int cn = lane & 15;
  const int quad = lane >> 4;
  const int bbase = blockIdx.x * MB;
  const int ju0 = (wv * 2) * 16 + cn;  // unit-group 0 column
  const int ju1 = ju0 + 16;            // unit-group 1 column

  // stage obs tile: [20][16][2] fp32 = 160 float4
  if (tid < OBS_T * MB * 2 / 4) {
    const int t = tid >> 3, f4 = tid & 7;
    ((float4*)obs_s)[tid] = ((const float4*)obs)[(t * batch + bbase) / 2 + f4];
  }
  // stage wx tables: 2 x 512 floats (scalar form — proven)
#pragma unroll
  for (int it = 0; it < 2; ++it) {
    int i = tid + it * 256;
    wx0_s[i] = wx0p[i];
    wx1_s[i] = wx1p[i];
  }
  // stage h0 tile fp32 -> bf16 LDS: 16 rows x 32 float4 = 512
#pragma unroll
  for (int it = 0; it < 2; ++it) {
    int idx = tid + it * 256;
    int row = idx >> 5, c4 = idx & 31;
    float4 v = ((const float4*)h0)[(bbase + row) * 32 + c4];
    bf16x4 b;
    b.x = (__bf16)v.x; b.y = (__bf16)v.y; b.z = (__bf16)v.z; b.w = (__bf16)v.w;
    *(bf16x4*)&hbuf[0][row][c4 * 4] = b;
  }

  // persistent B fragments: 2 unit-groups x 4 gates x 4 ksteps = 128 regs
  bf16x8 Bf[2][4][4];  // [u][ks][q]
  {
    const bf16x8* wp8 = (const bf16x8*)Wp;
#pragma unroll
    for (int u = 0; u < 2; ++u)
#pragma unroll
      for (int q = 0; q < 4; ++q)
#pragma unroll
        for (int ks = 0; ks < 4; ++ks)
          Bf[u][ks][q] = wp8[((wv * 2 + u) * 16 + q * 4 + ks) * 64 + lane];
  }

  // bias hoisted to regs (8): loop-invariant
  float bias_v[2][4];
#pragma unroll
  for (int u = 0; u < 2; ++u)
#pragma unroll
    for (int q = 0; q < 4; ++q)
      bias_v[u][q] = biasp[(wv * 2 + u) * 64 + q * 16 + cn];

  // c state: [u][r], rows m = quad*4+r, col ju_u — fp32 in regs
  float cc[2][4];
#pragma unroll
  for (int r = 0; r < 4; ++r) {
    cc[0][r] = c0[(bbase + quad * 4 + r) * HID + ju0];
    cc[1][r] = c0[(bbase + quad * 4 + r) * HID + ju1];
  }

  __syncthreads();

  int cur = 0;
#pragma unroll 1
  for (int t = 0; t < OBS_T - 1; ++t) {
    // acc init for BOTH groups: bias + rank-2 folded embedding (fp32, pre-scaled)
    f32x4 acc[2][4];  // [u][q]
#pragma unroll
    for (int u = 0; u < 2; ++u)
#pragma unroll
      for (int q = 0; q < 4; ++q) {
        int n = (wv * 2 + u) * 64 + q * 16 + cn;
        float w0q = wx0_s[n], w1q = wx1_s[n];
#pragma unroll
        for (int r = 0; r < 4; ++r) {
          float2 ob = *(const float2*)&obs_s[t][quad * 4 + r][0];
          acc[u][q][r] = fmaf(ob.y, w1q, fmaf(ob.x, w0q, bias_v[u][q]));
        }
      }

    // gates += h @ (scaled W_hh)^T : ONE A-load per ks, 32 MFMAs
#pragma unroll
    for (int ks = 0; ks < 4; ++ks) {
      bf16x8 Av = *(const bf16x8*)&hbuf[cur][cn][ks * 32 + quad * 8];
#pragma unroll
      for (int q = 0; q < 4; ++q) {
        acc[0][q] = __builtin_amdgcn_mfma_f32_16x16x32_bf16(Av, Bf[0][ks][q], acc[0][q], 0, 0, 0);
        acc[1][q] = __builtin_amdgcn_mfma_f32_16x16x32_bf16(Av, Bf[1][ks][q], acc[1][q], 0, 0, 0);
      }
    }

    // all 8 cell updates together (max transcendental ILP)
    const int nxt = cur ^ 1;
#pragma unroll
    for (int r = 0; r < 4; ++r) {
      float h0v = cell_update(acc[0][0][r], acc[0][1][r], acc[0][2][r], acc[0][3][r], cc[0][r]);
      float h1v = cell_update(acc[1][0][r], acc[1][1][r], acc[1][2][r], acc[1][3][r], cc[1][r]);
      hbuf[nxt][quad * 4 + r][ju0] = (__bf16)h0v;
      hbuf[nxt][quad * 4 + r][ju1] = (__bf16)h1v;
    }
    __syncthreads();
    cur = nxt;
  }

  // peeled final step: h straight to global
  {
    const int t = OBS_T - 1;
    f32x4 acc[2][4];
#pragma unroll
    for (int u = 0; u < 2; ++u)
#pragma unroll
      for (int q = 0; q < 4; ++q) {
        int n = (wv * 2 + u) * 64 + q * 16 + cn;
        float w0q = wx0_s[n], w1q = wx1_s[n];
#pragma unroll
        for (int r = 0; r < 4; ++r) {
          float2 ob = *(const float2*)&obs_s[t][quad * 4 + r][0];
          acc[u][q][r] = fmaf(ob.y, w1q, fmaf(ob.x, w0q, bias_v[u][q]));
        }
      }
#pragma unroll
    for (int ks = 0; ks < 4; ++ks) {
      bf16x8 Av = *(const bf16x8*)&hbuf[cur][cn][ks * 32 + quad * 8];
#pragma unroll
      for (int q = 0; q < 4; ++q) {
        acc[0][q] = __builtin_amdgcn_mfma_f32_16x16x32_bf16(Av, Bf[0][ks][q], acc[0][q], 0, 0, 0);
        acc[1][q] = __builtin_amdgcn_mfma_f32_16x16x32_bf16(Av, Bf[1][ks][q], acc[1][q], 0, 0, 0);
      }
    }
#pragma unroll
    for (int r = 0; r < 4; ++r) {
      float h0v = cell_update(acc[0][0][r], acc[0][1][r], acc[0][2][r], acc[0][3][r], cc[0][r]);
      float h1v = cell_update(acc[1][0][r], acc[1][1][r], acc[1][2][r], acc[1][3][r], cc[1][r]);
      out[(bbase + quad * 4 + r) * HID + ju0] = h0v;
      out[(bbase + quad * 4 + r) * HID + ju1] = h1v;
    }
  }
}

extern "C" void kernel_launch(void* const* d_in, const int* in_sizes, int n_in,
                              void* d_out, int out_size, void* d_ws, size_t ws_size,
                              hipStream_t stream) {
  const float* obs = (const float*)d_in[0];
  const float* h0 = (const float*)d_in[1];
  const float* c0 = (const float*)d_in[2];
  const float* W_emb = (const float*)d_in[3];
  const float* b_emb = (const float*)d_in[4];
  const float* W_ih = (const float*)d_in[5];
  const float* W_hh = (const float*)d_in[6];
  const float* b_ih = (const float*)d_in[7];
  const float* b_hh = (const float*)d_in[8];
  float* out = (float*)d_out;
  const int batch = in_sizes[1] / HID;

  __bf16* Wp = (__bf16*)d_ws;                     // 65536 bf16 = 128 KB
  float* biasp = (float*)((char*)d_ws + 131072);  // 3 x 512 f32
  float* wx0p = biasp + NGATE;
  float* wx1p = wx0p + NGATE;

  prep_vec<<<2, 256, 0, stream>>>(W_emb, b_emb, W_ih, b_ih, b_hh, biasp, wx0p, wx1p);
  prep_wp<<<256, 256, 0, stream>>>(W_hh, Wp);
  lstm_fused<<<batch / MB, 256, 0, stream>>>(obs, h0, c0, Wp, biasp, wx0p, wx1p, out, batch);
}